// Round 21
// baseline (326.637 us; speedup 1.0000x reference)
//
#include <hip/hip_runtime.h>
#include <hip/hip_bf16.h>

// Problem constants
#define NB 4
#define CDIM 192
#define HEADS 8
#define CP 24
#define HH 128
#define WW 128
#define NPIX 16384  // 128*128

typedef __hip_bfloat16 bf16;
typedef __bf16 bf16x8 __attribute__((ext_vector_type(8)));
typedef float f32x4 __attribute__((ext_vector_type(4)));
typedef float f32x16 __attribute__((ext_vector_type(16)));

__device__ __forceinline__ float toF(float v) { return v; }
__device__ __forceinline__ float toF(bf16 v) { return __bfloat162float(v); }
__device__ __forceinline__ void stF(float* p, float v) { *p = v; }
__device__ __forceinline__ void stF(bf16* p, float v) { *p = __float2bfloat16(v); }
__device__ __forceinline__ unsigned short bfbits(float v) {
    bf16 h = __float2bfloat16(v);
    return *reinterpret_cast<unsigned short*>(&h);
}
__device__ __forceinline__ float b2f(unsigned short u) {
    union { unsigned int i; float f; } c;
    c.i = ((unsigned int)u) << 16;
    return c.f;
}

// ===========================================================================
// Packing helpers.
// 1x1: lane-ordered for 16x16x32 (unchanged).
// conv: lane-ordered for 32x32x16 A-frag: oc=lane&31, k=(lane>>5)*8+j,
//       [oc32][tap 9][ksg16 12][lane 64][8].
// ===========================================================================
__device__ __forceinline__ void pack1x1_elem(
    const float* __restrict__ w, unsigned short* __restrict__ wp, int e, int IC)
{
    int j = e & 7, lane = (e >> 3) & 63, rest = e >> 9;
    int nks = IC >> 5;
    int ksg = rest % nks, oc16 = rest / nks;
    int oc = oc16 * 16 + (lane & 15);
    int ic = ksg * 32 + (lane >> 4) * 8 + j;
    wp[e] = bfbits(w[(long long)oc * IC + ic]);
}

__device__ __forceinline__ void packconv_elem(
    const float* __restrict__ w, unsigned short* __restrict__ wp, int e)
{
    int j = e & 7, lane = (e >> 3) & 63, rest = e >> 9;
    int ksg = rest % 12; rest /= 12;
    int tap = rest % 9;
    int oc32 = rest / 9;
    int oc = oc32 * 32 + (lane & 31);
    int ic = ksg * 16 + (lane >> 5) * 8 + j;
    wp[e] = bfbits(w[((long long)oc * 192 + ic) * 9 + tap]);
}

// One fused prep kernel: zero stats + all four weight packs.
__global__ __launch_bounds__(256) void prep_kernel(
    float* __restrict__ stats,
    const float* __restrict__ q_w, unsigned short* __restrict__ qwb,
    const float* __restrict__ newk_w, unsigned short* __restrict__ nkb,
    const float* __restrict__ newv_w, unsigned short* __restrict__ nvb,
    const float* __restrict__ kv_w, unsigned short* __restrict__ wpack)
{
    int idx = blockIdx.x * 256 + threadIdx.x;
    if (idx < 20736) { stats[idx] = 0.f; return; }
    idx -= 20736;
    if (idx < 110592) { pack1x1_elem(q_w, qwb, idx, 192); return; }
    idx -= 110592;
    if (idx < 73728) { pack1x1_elem(newk_w, nkb, idx, 384); return; }
    idx -= 73728;
    if (idx < 73728) { pack1x1_elem(newv_w, nvb, idx, 384); return; }
    idx -= 73728;
    if (idx < 663552) { packconv_elem(kv_w, wpack, idx); }
}

// ---------------------------------------------------------------------------
// 1x1-conv GEMM via bf16 MFMA, stage-K-once + B-fragments hoisted to
// registers (unchanged).
// ---------------------------------------------------------------------------
template <typename TI, typename TO, int IC, int OCT, int ICPAD>
__device__ __forceinline__ void gemm1x1_body(
    const TI* __restrict__ in0, long long bs0,
    const TI* __restrict__ in1, long long bs1, int ic_split,
    const unsigned short* __restrict__ Wbf, long long w_bs,
    const float* __restrict__ bias,
    TO* __restrict__ out, long long bs_out,
    unsigned short (*xs)[ICPAD])
{
    int tid = threadIdx.x;
    int lane = tid & 63;
    int wave = tid >> 6;
    int w_oc = wave >> 1;
    int w_px = wave & 1;
    int l15 = lane & 15;
    int lk  = lane >> 4;
    constexpr int NKS = IC / 32;

    int nb = blockIdx.x * 64;
    int b  = blockIdx.z;
    const unsigned short* Wb = Wbf + (long long)b * w_bs;

    for (int u = tid; u < (IC / 4) * 16; u += 256) {
        int px = (u & 15) * 4;
        int ic = (u >> 4) * 4;
        unsigned short rb[4][4];
#pragma unroll
        for (int j = 0; j < 4; ++j) {
            int ch = ic + j;
            const TI* p;
            if (ch < ic_split)
                p = in0 + (long long)b * bs0 + (long long)ch * NPIX + nb + px;
            else
                p = in1 + (long long)b * bs1 + (long long)(ch - ic_split) * NPIX + nb + px;
            if constexpr (sizeof(TI) == 4) {
                float4 v = *reinterpret_cast<const float4*>(p);
                rb[j][0] = bfbits(v.x); rb[j][1] = bfbits(v.y);
                rb[j][2] = bfbits(v.z); rb[j][3] = bfbits(v.w);
            } else {
                ushort4 v = *reinterpret_cast<const ushort4*>(p);
                rb[j][0] = v.x; rb[j][1] = v.y; rb[j][2] = v.z; rb[j][3] = v.w;
            }
        }
        int swz = ((px >> 2) & 7) * 8;
#pragma unroll
        for (int i = 0; i < 4; ++i) {
            union { unsigned short s[4]; uint2 v; } pk;
            pk.s[0] = rb[0][i]; pk.s[1] = rb[1][i];
            pk.s[2] = rb[2][i]; pk.s[3] = rb[3][i];
            *reinterpret_cast<uint2*>(&xs[px + i][ic ^ swz]) = pk.v;
        }
    }
    __syncthreads();

    int pxw = w_px * 32;

    bf16x8 bvreg[NKS][2];
#pragma unroll
    for (int ks = 0; ks < NKS; ++ks) {
        int koff = ks * 32 + lk * 8;
#pragma unroll
        for (int nf = 0; nf < 2; ++nf) {
            int px = pxw + nf * 16 + l15;
            int swzr = ((px >> 2) & 7) * 8;
            bvreg[ks][nf] = *reinterpret_cast<const bf16x8*>(&xs[px][koff ^ swzr]);
        }
    }

    __builtin_amdgcn_s_setprio(1);
#pragma unroll 1
    for (int ot = 0; ot < OCT; ++ot) {
        int ocw = ot * 64 + w_oc * 32;
        int oc16g = ot * 4 + w_oc * 2;
        f32x4 acc[2][2];
#pragma unroll
        for (int mi = 0; mi < 2; ++mi)
#pragma unroll
            for (int r = 0; r < 4; ++r) {
                float bz = bias[ocw + mi * 16 + lk * 4 + r];
#pragma unroll
                for (int nf = 0; nf < 2; ++nf) acc[mi][nf][r] = bz;
            }

#pragma unroll
        for (int ks = 0; ks < NKS; ++ks) {
            bf16x8 a[2];
#pragma unroll
            for (int mi = 0; mi < 2; ++mi)
                a[mi] = *reinterpret_cast<const bf16x8*>(
                    &Wb[((long long)(oc16g + mi) * NKS + ks) * 512 + lane * 8]);
#pragma unroll
            for (int mi = 0; mi < 2; ++mi)
#pragma unroll
                for (int nf = 0; nf < 2; ++nf)
                    acc[mi][nf] = __builtin_amdgcn_mfma_f32_16x16x32_bf16(
                        a[mi], bvreg[ks][nf], acc[mi][nf], 0, 0, 0);
        }

#pragma unroll
        for (int mi = 0; mi < 2; ++mi)
#pragma unroll
            for (int nf = 0; nf < 2; ++nf) {
                int x = pxw + nf * 16 + l15;
#pragma unroll
                for (int r = 0; r < 4; ++r) {
                    int oc = ocw + mi * 16 + lk * 4 + r;
                    stF(&out[(long long)b * bs_out + (long long)oc * NPIX + nb + x],
                        acc[mi][nf][r]);
                }
            }
    }
    __builtin_amdgcn_s_setprio(0);
}

template <typename TI, typename TO, int IC, int OCT, int ICPAD>
__global__ __launch_bounds__(256) void gemm1x1_allK_kernel(
    const TI* __restrict__ in0, long long bs0,
    const TI* __restrict__ in1, long long bs1, int ic_split,
    const unsigned short* __restrict__ Wbf, long long w_bs,
    const float* __restrict__ bias,
    TO* __restrict__ out, long long bs_out)
{
    __shared__ unsigned short xs[64][ICPAD];
    gemm1x1_body<TI, TO, IC, OCT, ICPAD>(in0, bs0, in1, bs1, ic_split,
                                         Wbf, w_bs, bias, out, bs_out, xs);
}

// Dual variant: blockIdx.y selects set A (k) or set B (v).
template <typename TI, typename TO, int IC, int OCT, int ICPAD>
__global__ __launch_bounds__(256) void gemm1x1_dual_kernel(
    const TI* __restrict__ in0a, const TI* __restrict__ in1a,
    const unsigned short* __restrict__ Wa, const float* __restrict__ biasa,
    TO* __restrict__ outa,
    const TI* __restrict__ in0b, const TI* __restrict__ in1b,
    const unsigned short* __restrict__ Wb_, const float* __restrict__ biasb,
    TO* __restrict__ outb,
    long long bs0, long long bs1, int ic_split, long long bs_out)
{
    __shared__ unsigned short xs[64][ICPAD];
    int y = blockIdx.y;
    gemm1x1_body<TI, TO, IC, OCT, ICPAD>(
        y ? in0b : in0a, bs0, y ? in1b : in1a, bs1, ic_split,
        y ? Wb_ : Wa, 0, y ? biasb : biasa, y ? outb : outa, bs_out, xs);
}

// ---------------------------------------------------------------------------
// Grouped / depthwise 3x3 conv, pad 1 — register sliding window.
// ---------------------------------------------------------------------------
template <int GIN, int GOUT, int ROWS>
__global__ __launch_bounds__(256) void dwconv3x3_kernel(
    const bf16* __restrict__ in, const float* __restrict__ Wm,
    const float* __restrict__ bias, bf16* __restrict__ out, int groups)
{
    __shared__ float xs[GIN][ROWS + 2][136];
    int tid = threadIdx.x;
    int g = blockIdx.y;
    int b = blockIdx.z;
    int y0 = blockIdx.x * ROWS;
    long long bsin = (long long)groups * GIN * NPIX;
    long long bsout = (long long)groups * GOUT * NPIX;
    const bf16* inb = in + (long long)b * bsin;

    constexpr int NLOAD = GIN * (ROWS + 2) * 32;
    for (int idx = tid; idx < NLOAD; idx += 256) {
        int seg = idx & 31;
        int r = (idx >> 5) % (ROWS + 2);
        int ic = idx / (32 * (ROWS + 2));
        int yy = y0 + r - 1;
        float4 f = {0.f, 0.f, 0.f, 0.f};
        if (yy >= 0 && yy < HH) {
            ushort4 u = *reinterpret_cast<const ushort4*>(
                &inb[(long long)(g * GIN + ic) * NPIX + yy * WW + seg * 4]);
            f.x = b2f(u.x); f.y = b2f(u.y); f.z = b2f(u.z); f.w = b2f(u.w);
        }
        *reinterpret_cast<float4*>(&xs[ic][r][seg * 4 + 4]) = f;
    }
    for (int idx = tid; idx < GIN * (ROWS + 2); idx += 256) {
        int r = idx % (ROWS + 2), ic = idx / (ROWS + 2);
        xs[ic][r][3] = 0.f;
        xs[ic][r][132] = 0.f;
    }
    __syncthreads();

    int x = tid & 127;
    int half = tid >> 7;
    constexpr int HR = ROWS / 2;
    int ry0 = half * HR;

    float wreg[GOUT][GIN][9];
    float bz[GOUT];
#pragma unroll
    for (int oc = 0; oc < GOUT; ++oc) {
        bz[oc] = bias[g * GOUT + oc];
#pragma unroll
        for (int ic = 0; ic < GIN; ++ic)
#pragma unroll
            for (int t = 0; t < 9; ++t)
                wreg[oc][ic][t] = Wm[((long long)(g * GOUT + oc) * GIN + ic) * 9 + t];
    }

    float win[GIN][3][3];
#pragma unroll
    for (int ic = 0; ic < GIN; ++ic)
#pragma unroll
        for (int pr = 0; pr < 2; ++pr)
#pragma unroll
            for (int kx = 0; kx < 3; ++kx)
                win[ic][pr][kx] = xs[ic][ry0 + pr][x + 3 + kx];

#pragma unroll
    for (int rr = 0; rr < HR; ++rr) {
#pragma unroll
        for (int ic = 0; ic < GIN; ++ic)
#pragma unroll
            for (int kx = 0; kx < 3; ++kx)
                win[ic][(rr + 2) % 3][kx] = xs[ic][ry0 + rr + 2][x + 3 + kx];
#pragma unroll
        for (int oc = 0; oc < GOUT; ++oc) {
            float acc = bz[oc];
#pragma unroll
            for (int ic = 0; ic < GIN; ++ic)
#pragma unroll
                for (int ky = 0; ky < 3; ++ky)
#pragma unroll
                    for (int kx = 0; kx < 3; ++kx)
                        acc = fmaf(wreg[oc][ic][ky * 3 + kx],
                                   win[ic][(rr + ky) % 3][kx], acc);
            stF(&out[(long long)b * bsout + (long long)(g * GOUT + oc) * NPIX
                     + (y0 + ry0 + rr) * WW + x], acc);
        }
    }
}

// ---------------------------------------------------------------------------
// NCHW fp32 -> NHWC bf16 transpose-convert (unchanged).
// ---------------------------------------------------------------------------
__global__ __launch_bounds__(256) void nchw2nhwc_kernel(
    const float* __restrict__ in, unsigned short* __restrict__ outp)
{
    __shared__ float xs[192][65];
    int tid = threadIdx.x;
    int y = blockIdx.x >> 1;
    int x0 = (blockIdx.x & 1) * 64;
    int b = blockIdx.z;

    for (int idx = tid; idx < 192 * 64; idx += 256) {
        int ic = idx >> 6, px = idx & 63;
        xs[ic][px] = in[(((long long)b * CDIM + ic) << 14) + y * WW + x0 + px];
    }
    __syncthreads();
    for (int idx = tid; idx < 64 * 24; idx += 256) {
        int px = idx / 24, grp = idx % 24;
        union { unsigned short u[8]; uint4 v; } pk;
#pragma unroll
        for (int j = 0; j < 8; ++j) pk.u[j] = bfbits(xs[grp * 8 + j][px]);
        *reinterpret_cast<uint4*>(
            &outp[(((long long)b * HH + y) * WW + x0 + px) * CDIM + grp * 8]) = pk.v;
    }
}

// ---------------------------------------------------------------------------
// Dense 3x3 conv 192->384, now via 32x32x16 MFMA (m119: +17% pipe
// throughput vs 16x16x32; halves MFMA instruction count). Same R18/R20
// shell: 2-output-row tiles, double-buffered global_load_lds staging,
// 4 waves = 2 oc-halves x 2 px-halves; wave = 64 oc (2x 32-tiles) x 32 px.
// A-frag (32x32): oc=lane&31, k=(lane>>5)*8+j from repacked Wc.
// B-frag: col(px)=lane&31, k-group g2=ksl*2+(lane>>5) from swizzled LDS.
// C/D: col=lane&31, row=(reg&3)+8*(reg>>2)+4*(lane>>5)  [m74/m101].
// ---------------------------------------------------------------------------
__global__ __launch_bounds__(256) void conv3x3_mfma_kernel(
    const unsigned short* __restrict__ Xbf,
    const unsigned short* __restrict__ Wc,
    const float* __restrict__ bias,
    const unsigned short* __restrict__ zsrc,
    bf16* __restrict__ out)
{
    __shared__ unsigned short xs[2][4][66][64];
    int tid = threadIdx.x;
    int lane = tid & 63;
    int wave = tid >> 6;        // 0..3
    int w_oc = wave >> 1;       // 0..1
    int w_px = wave & 1;        // 0..1
    int l31 = lane & 31;
    int lh  = lane >> 5;        // 0..1

    int ypair = blockIdx.x >> 1;
    int xstart = (blockIdx.x & 1) * 64;
    int y0 = ypair * 2;
    int b = blockIdx.z;
    int ocw = blockIdx.y * 128 + w_oc * 64;
    int oc32base = blockIdx.y * 4 + w_oc * 2;

    f32x16 acc[2][2];  // [yo][mi]
#pragma unroll
    for (int mi = 0; mi < 2; ++mi)
#pragma unroll
        for (int r0 = 0; r0 < 16; ++r0) {
            float bz = bias[ocw + mi * 32 + (r0 & 3) + 8 * (r0 >> 2) + 4 * lh];
#pragma unroll
            for (int yo = 0; yo < 2; ++yo) acc[yo][mi][r0] = bz;
        }

#define CONV_GLL_CHUNK(IC0, BUF)                                               \
    {                                                                          \
        _Pragma("unroll")                                                      \
        for (int k = 0; k < 9; ++k) {                                          \
            if (k < 8 || wave == 0) {                                          \
                int idx = (k << 8) + (wave << 6) + lane;                       \
                int r = idx / 528;                                             \
                int rem = idx - r * 528;                                       \
                int col = rem >> 3;                                            \
                int grp = rem & 7;                                             \
                int g = grp ^ (col & 7);                                       \
                int yy = y0 + r - 1;                                           \
                int xx = xstart + col - 1;                                     \
                const unsigned short* src =                                    \
                    (yy >= 0 && yy < HH && xx >= 0 && xx < WW)                 \
                        ? &Xbf[(((long long)b * HH + yy) * WW + xx) * CDIM     \
                               + (IC0) + g * 8]                                \
                        : zsrc;                                                \
                unsigned short* lptr = ((unsigned short*)xs) +                 \
                    (BUF) * (4 * 66 * 64) + (((k << 8) + (wave << 6)) << 3);   \
                __builtin_amdgcn_global_load_lds(                              \
                    (const __attribute__((address_space(1))) unsigned int*)src,\
                    (__attribute__((address_space(3))) unsigned int*)lptr,     \
                    16, 0, 0);                                                 \
            }                                                                  \
        }                                                                      \
    }

    CONV_GLL_CHUNK(0, 0);

#pragma unroll
    for (int chunk = 0; chunk < 3; ++chunk) {
        __syncthreads();  // drains vmcnt: this chunk's buffer is ready
        if (chunk == 0)      { CONV_GLL_CHUNK(64, 1); }   // overlap with compute
        else if (chunk == 1) { CONV_GLL_CHUNK(128, 0); }
        int buf = chunk & 1;
        __builtin_amdgcn_s_setprio(1);

#pragma unroll
        for (int kx = 0; kx < 3; ++kx) {
#pragma unroll
            for (int ksl = 0; ksl < 4; ++ksl) {
                int ksg = chunk * 4 + ksl;
                // A-frags for 3 ky x 2 mi (32x32 layout), coalesced 1KB loads
                bf16x8 aw[3][2];
#pragma unroll
                for (int ky = 0; ky < 3; ++ky)
#pragma unroll
                    for (int mi = 0; mi < 2; ++mi)
                        aw[ky][mi] = *reinterpret_cast<const bf16x8*>(
                            &Wc[((((long long)(oc32base + mi) * 9 + ky * 3 + kx) * 12 + ksg)
                                 << 9) + lane * 8]);
#pragma unroll
                for (int r = 0; r < 4; ++r) {
                    int col = w_px * 32 + l31 + kx;
                    int g2 = ksl * 2 + lh;
                    int slot = g2 ^ (col & 7);
                    bf16x8 bv = *reinterpret_cast<const bf16x8*>(
                        &xs[buf][r][col][slot * 8]);
#pragma unroll
                    for (int yo = 0; yo < 2; ++yo) {
                        int ky = r - yo;
                        if (ky >= 0 && ky <= 2) {
#pragma unroll
                            for (int mi = 0; mi < 2; ++mi)
                                acc[yo][mi] = __builtin_amdgcn_mfma_f32_32x32x16_bf16(
                                    aw[ky][mi], bv, acc[yo][mi], 0, 0, 0);
                        }
                    }
                }
            }
        }
        __builtin_amdgcn_s_setprio(0);
    }

    int x = xstart + w_px * 32 + l31;
#pragma unroll
    for (int yo = 0; yo < 2; ++yo)
#pragma unroll
        for (int mi = 0; mi < 2; ++mi)
#pragma unroll
            for (int r0 = 0; r0 < 16; ++r0) {
                int oc = ocw + mi * 32 + (r0 & 3) + 8 * (r0 >> 2) + 4 * lh;
                stF(&out[(((long long)b * 384 + oc) << 14) + (y0 + yo) * WW + x],
                    acc[yo][mi][r0]);
            }
}

// ---------------------------------------------------------------------------
// Gram + sumsq via MFMA (unchanged from R8).
// ---------------------------------------------------------------------------
__global__ __launch_bounds__(256) void gram_mfma_kernel(
    const unsigned short* __restrict__ q, long long bsq,
    const unsigned short* __restrict__ k, long long bsk,
    const unsigned short* __restrict__ v, long long bsv,
    float* __restrict__ ssq, float* __restrict__ gram)
{
    __shared__ float gl[4][24][25];
    int bh = blockIdx.x;
    int b = bh >> 3, h = bh & 7;
    int n0 = blockIdx.y * 1024;
    int tid = threadIdx.x;
    int lane = tid & 63;
    int wave = tid >> 6;
    int l15 = lane & 15;
    int lk = lane >> 4;

    const unsigned short* qb = q + (long long)b * bsq + (long long)(h * CP) * NPIX;
    const unsigned short* kb = k + (long long)b * bsk + (long long)(h * CP) * NPIX;
    const unsigned short* vb = v + (long long)b * bsv + (long long)(h * CP) * NPIX;

    f32x4 acc[2][2], aqq[2], akk[2], avv[2];
#pragma unroll
    for (int mt = 0; mt < 2; ++mt) {
#pragma unroll
        for (int nt = 0; nt < 2; ++nt) acc[mt][nt] = {0.f, 0.f, 0.f, 0.f};
        aqq[mt] = {0.f, 0.f, 0.f, 0.f};
        akk[mt] = {0.f, 0.f, 0.f, 0.f};
        avv[mt] = {0.f, 0.f, 0.f, 0.f};
    }

#pragma unroll 2
    for (int st = 0; st < 8; ++st) {
        int px = n0 + wave * 256 + st * 32 + lk * 8;
        bf16x8 aq[2], bk[2], av[2];
#pragma unroll
        for (int mt = 0; mt < 2; ++mt) {
            long long off = (long long)(mt * 16 + l15) * NPIX + px;
            aq[mt] = *reinterpret_cast<const bf16x8*>(&qb[off]);
            bk[mt] = *reinterpret_cast<const bf16x8*>(&kb[off]);
            av[mt] = *reinterpret_cast<const bf16x8*>(&vb[off]);
        }
#pragma unroll
        for (int mt = 0; mt < 2; ++mt)
#pragma unroll
            for (int nt = 0; nt < 2; ++nt)
                acc[mt][nt] = __builtin_amdgcn_mfma_f32_16x16x32_bf16(
                    aq[mt], bk[nt], acc[mt][nt], 0, 0, 0);
#pragma unroll
        for (int mt = 0; mt < 2; ++mt) {
            aqq[mt] = __builtin_amdgcn_mfma_f32_16x16x32_bf16(aq[mt], aq[mt], aqq[mt], 0, 0, 0);
            akk[mt] = __builtin_amdgcn_mfma_f32_16x16x32_bf16(bk[mt], bk[mt], akk[mt], 0, 0, 0);
            avv[mt] = __builtin_amdgcn_mfma_f32_16x16x32_bf16(av[mt], av[mt], avv[mt], 0, 0, 0);
        }
    }

    if (lk == (l15 >> 2)) {
        int r = l15 & 3;
#pragma unroll
        for (int mt = 0; mt < 2; ++mt) {
            int ch = mt * 16 + l15;
            if (ch < CP) {
                int o = b * CDIM + h * CP + ch;
                atomicAdd(&ssq[o], aqq[mt][r]);
                atomicAdd(&ssq[NB * CDIM + o], akk[mt][r]);
                atomicAdd(&ssq[2 * NB * CDIM + o], avv[mt][r]);
            }
        }
    }

#pragma unroll
    for (int mt = 0; mt < 2; ++mt)
#pragma unroll
        for (int nt = 0; nt < 2; ++nt)
#pragma unroll
            for (int r = 0; r < 4; ++r) {
                int cq = mt * 16 + lk * 4 + r;
                int ck = nt * 16 + l15;
                if (cq < CP && ck < CP) gl[wave][cq][ck] = acc[mt][nt][r];
            }
    __syncthreads();
    for (int e = tid; e < CP * CP; e += 256) {
        int cq = e / CP, ck = e % CP;
        float s = gl[0][cq][ck] + gl[1][cq][ck] + gl[2][cq][ck] + gl[3][cq][ck];
        atomicAdd(&gram[(long long)bh * (CP * CP) + e], s);
    }
}

// ---------------------------------------------------------------------------
// Softmax + fold norms + proj -> per-batch M, packed layout (R16 parallel).
// ---------------------------------------------------------------------------
__global__ __launch_bounds__(256) void build_M_kernel(
    const float* __restrict__ ssq, const float* __restrict__ gram,
    const float* __restrict__ temp, const float* __restrict__ proj_w,
    unsigned short* __restrict__ Mout)
{
    __shared__ float A[HEADS][CP][CP + 1];
    __shared__ float nv[CDIM];
    int b = blockIdx.x;
    int ocg = blockIdx.y;           // 0..23, 8 ocs each
    int tid = threadIdx.x;

    if (tid < CDIM)
        nv[tid] = fmaxf(sqrtf(ssq[2 * (NB * CDIM) + b * CDIM + tid]), 1e-12f);
    __syncthreads();
    if (tid < CDIM) {
        int h = tid / CP, cq = tid % CP;
        float t = temp[h];
        float nq = fmaxf(sqrtf(ssq[0 * (NB * CDIM) + b * CDIM + tid]), 1e-12f);
        float row[CP];
        float m = -1e30f;
#pragma unroll
        for (int ck = 0; ck < CP; ++ck) {
            float nk = fmaxf(sqrtf(ssq[1 * (NB * CDIM) + b * CDIM + h * CP + ck]), 1e-12f);
            float g = gram[(long long)b * (HEADS * 576) + h * 576 + cq * CP + ck];
            g = g / (nq * nk) * t;
            row[ck] = g;
            m = fmaxf(m, g);
        }
        float s = 0.f;
#pragma unroll
        for (int ck = 0; ck < CP; ++ck) { row[ck] = __expf(row[ck] - m); s += row[ck]; }
        float inv = 1.f / s;
#pragma unroll
        for (int ck = 0; ck < CP; ++ck)
            A[h][cq][ck] = row[ck] * inv / nv[h * CP + ck];
    }
    __syncthreads();
    for (int e = tid; e < 8 * CDIM; e += 256) {
        int oc = ocg * 8 + e / CDIM, d = e % CDIM;
        int h2 = d / CP, ck = d % CP;
        float acc = 0.f;
#pragma unroll
        for (int cq = 0; cq < CP; ++cq)
            acc = fmaf(proj_w[(long long)oc * CDIM + h2 * CP + cq], A[h2][cq][ck], acc);
        int oc16 = oc >> 4, l15 = oc & 15;
        int ksg = d >> 5, lk = (d >> 3) & 3, j = d & 7;
        int lanep = lk * 16 + l15;
        Mout[(long long)b * (CDIM * CDIM) + (((oc16 * 6 + ksg) << 6) + lanep) * 8 + j] =
            bfbits(acc);
    }
}

// ---------------------------------------------------------------------------
// Workspace layout (< 202 MB, extent identical to R14-R20).
// ---------------------------------------------------------------------------
extern "C" void kernel_launch(void* const* d_in, const int* in_sizes, int n_in,
                              void* d_out, int out_size, void* d_ws, size_t ws_size,
                              hipStream_t stream)
{
    const float* x      = (const float*)d_in[0];
    const float* x_mask = (const float*)d_in[1];
    const float* temp   = (const float*)d_in[2];
    const float* q_w    = (const float*)d_in[3];
    const float* q_b    = (const float*)d_in[4];
    const float* qdw_w  = (const float*)d_in[5];
    const float* qdw_b  = (const float*)d_in[6];
    const float* kv_w   = (const float*)d_in[7];
    const float* kv_b   = (const float*)d_in[8];
    const float* kvdw_w = (const float*)d_in[9];
    const float* kvdw_b = (const float*)d_in[10];
    const float* newk_w = (const float*)d_in[11];
    const float* newk_b = (const float*)d_in[12];
    const float* newv_w = (const float*)d_in[13];
    const float* newv_b = (const float*)d_in[14];
    const float* proj_w = (const float*)d_in[15];
    const float* proj_b = (const float*)d_in[16];

    char* wsb = (char*)d_ws;
    bf16* A  = (bf16*)wsb;
    bf16* Bq = (bf16*)(wsb + 75497472);
    bf16* C  = (bf16*)(wsb + 150994944);
    unsigned short* qwb   = (unsigned short*)Bq;                    // 110,592
    unsigned short* Wpack = (unsigned short*)C;                     // 663,552
    unsigned short* Xbf   = (unsigned short*)C + 663552;            // 12,582,912
    float* stats = (float*)(wsb + 201326592);
    float* ssq  = stats;                                            // 2304
    float* gram = ssq + 2304;                                       // 18432
    unsigned short* nkb = (unsigned short*)(stats + 20736);         // 73,728
    unsigned short* nvb = nkb + 73728;                              // 73,728
    unsigned short* Mbf = nvb + 73728;                              // 147,456

    const long long N = NPIX;
    float* out = (float*)d_out;

    // P0: fused prep — zero stats + all weight packs (1 launch)
    prep_kernel<<<3681, 256, 0, stream>>>(
        stats, q_w, qwb, newk_w, nkb, newv_w, nvb, kv_w, Wpack);

    // S1: qkv1 = conv1x1(x, q_w) : 192 -> 576 (fp32 in, bf16 out) -> A
    gemm1x1_allK_kernel<float, bf16, 192, 9, 200><<<dim3(256, 1, 4), 256, 0, stream>>>(
        x, 192 * N, x, 0, 192, qwb, 0, q_b, A, 576 * N);

    // S2: qkv = grouped 3x3 (groups=192, 3in/3out) -> B (ROWS=16)
    dwconv3x3_kernel<3, 3, 16><<<dim3(8, 192, 4), 256, 0, stream>>>(
        A, qdw_w, qdw_b, Bq, 192);

    // NHWC convert into C (x_mask -> Xbf)
    nchw2nhwc_kernel<<<dim3(256, 1, 4), 256, 0, stream>>>(x_mask, Xbf);

    // S3: kv1 = dense conv3x3(x_mask) 192->384 via 32x32 MFMA -> A[0:25.17M)
    conv3x3_mfma_kernel<<<dim3(128, 3, 4), 256, 0, stream>>>(
        Xbf, Wpack, kv_b, (const unsigned short*)stats, A);

    // S4: kv2 = depthwise 3x3 (384 groups) -> C (ROWS=32)
    dwconv3x3_kernel<1, 1, 32><<<dim3(4, 384, 4), 256, 0, stream>>>(
        A, kvdw_w, kvdw_b, C, 384);

    // S5: k_new / v_new = conv1x1 of concat (IC=384), fused dual launch
    bf16* k_new = A;
    bf16* v_new = A + 12582912;
    gemm1x1_dual_kernel<bf16, bf16, 384, 3, 392><<<dim3(256, 2, 4), 256, 0, stream>>>(
        Bq + 192 * N, C, nkb, newk_b, k_new,
        Bq + 384 * N, C + 192 * N, nvb, newv_b, v_new,
        576 * N, 384 * N, 192, 192 * N);

    // S6: sumsq(q,k,v) + Gram(q,k) via MFMA
    gram_mfma_kernel<<<dim3(32, 16), 256, 0, stream>>>(
        (const unsigned short*)Bq, 576 * N,
        (const unsigned short*)k_new, 192 * N,
        (const unsigned short*)v_new, 192 * N, ssq, gram);

    // S7: softmax + fold v-norm + proj -> per-batch M (bf16, packed layout)
    build_M_kernel<<<dim3(4, 24), 256, 0, stream>>>(ssq, gram, temp, proj_w, Mbf);

    // S8: out = M_b @ v_new + proj_b (bf16 in, fp32 out)
    gemm1x1_allK_kernel<bf16, float, 192, 3, 200><<<dim3(256, 1, 4), 256, 0, stream>>>(
        v_new, 192 * N, v_new, 0, 192, Mbf, (long long)CDIM * CDIM, proj_b, out, 192 * N);
}

// Round 22
// 305.609 us; speedup vs baseline: 1.0688x; 1.0688x over previous
//
#include <hip/hip_runtime.h>
#include <hip/hip_bf16.h>

// Problem constants
#define NB 4
#define CDIM 192
#define HEADS 8
#define CP 24
#define HH 128
#define WW 128
#define NPIX 16384  // 128*128

typedef __hip_bfloat16 bf16;
typedef __bf16 bf16x8 __attribute__((ext_vector_type(8)));
typedef float f32x4 __attribute__((ext_vector_type(4)));

__device__ __forceinline__ float toF(float v) { return v; }
__device__ __forceinline__ float toF(bf16 v) { return __bfloat162float(v); }
__device__ __forceinline__ void stF(float* p, float v) { *p = v; }
__device__ __forceinline__ void stF(bf16* p, float v) { *p = __float2bfloat16(v); }
__device__ __forceinline__ unsigned short bfbits(float v) {
    bf16 h = __float2bfloat16(v);
    return *reinterpret_cast<unsigned short*>(&h);
}
__device__ __forceinline__ float b2f(unsigned short u) {
    union { unsigned int i; float f; } c;
    c.i = ((unsigned int)u) << 16;
    return c.f;
}

// ===========================================================================
// Packing helpers (lane-ordered coalesced MFMA A-operand layout, 16x16x32).
// ===========================================================================
__device__ __forceinline__ void pack1x1_elem(
    const float* __restrict__ w, unsigned short* __restrict__ wp, int e, int IC)
{
    int j = e & 7, lane = (e >> 3) & 63, rest = e >> 9;
    int nks = IC >> 5;
    int ksg = rest % nks, oc16 = rest / nks;
    int oc = oc16 * 16 + (lane & 15);
    int ic = ksg * 32 + (lane >> 4) * 8 + j;
    wp[e] = bfbits(w[(long long)oc * IC + ic]);
}

__device__ __forceinline__ void packconv_elem(
    const float* __restrict__ w, unsigned short* __restrict__ wp, int e)
{
    int j = e & 7, lane = (e >> 3) & 63, rest = e >> 9;
    int ksg = rest % 6; rest /= 6;
    int tap = rest % 9;
    int oc16 = rest / 9;
    int oc = oc16 * 16 + (lane & 15);
    int ic = ksg * 32 + (lane >> 4) * 8 + j;
    wp[e] = bfbits(w[((long long)oc * 192 + ic) * 9 + tap]);
}

// One fused prep kernel: zero stats + all four weight packs.
__global__ __launch_bounds__(256) void prep_kernel(
    float* __restrict__ stats,
    const float* __restrict__ q_w, unsigned short* __restrict__ qwb,
    const float* __restrict__ newk_w, unsigned short* __restrict__ nkb,
    const float* __restrict__ newv_w, unsigned short* __restrict__ nvb,
    const float* __restrict__ kv_w, unsigned short* __restrict__ wpack)
{
    int idx = blockIdx.x * 256 + threadIdx.x;
    if (idx < 20736) { stats[idx] = 0.f; return; }
    idx -= 20736;
    if (idx < 110592) { pack1x1_elem(q_w, qwb, idx, 192); return; }
    idx -= 110592;
    if (idx < 73728) { pack1x1_elem(newk_w, nkb, idx, 384); return; }
    idx -= 73728;
    if (idx < 73728) { pack1x1_elem(newv_w, nvb, idx, 384); return; }
    idx -= 73728;
    if (idx < 663552) { packconv_elem(kv_w, wpack, idx); }
}

// ---------------------------------------------------------------------------
// 1x1-conv GEMM via bf16 MFMA, stage-K-once + B-fragments hoisted to
// registers.
// ---------------------------------------------------------------------------
template <typename TI, typename TO, int IC, int OCT, int ICPAD>
__device__ __forceinline__ void gemm1x1_body(
    const TI* __restrict__ in0, long long bs0,
    const TI* __restrict__ in1, long long bs1, int ic_split,
    const unsigned short* __restrict__ Wbf, long long w_bs,
    const float* __restrict__ bias,
    TO* __restrict__ out, long long bs_out,
    unsigned short (*xs)[ICPAD])
{
    int tid = threadIdx.x;
    int lane = tid & 63;
    int wave = tid >> 6;
    int w_oc = wave >> 1;
    int w_px = wave & 1;
    int l15 = lane & 15;
    int lk  = lane >> 4;
    constexpr int NKS = IC / 32;

    int nb = blockIdx.x * 64;
    int b  = blockIdx.z;
    const unsigned short* Wb = Wbf + (long long)b * w_bs;

    for (int u = tid; u < (IC / 4) * 16; u += 256) {
        int px = (u & 15) * 4;
        int ic = (u >> 4) * 4;
        unsigned short rb[4][4];
#pragma unroll
        for (int j = 0; j < 4; ++j) {
            int ch = ic + j;
            const TI* p;
            if (ch < ic_split)
                p = in0 + (long long)b * bs0 + (long long)ch * NPIX + nb + px;
            else
                p = in1 + (long long)b * bs1 + (long long)(ch - ic_split) * NPIX + nb + px;
            if constexpr (sizeof(TI) == 4) {
                float4 v = *reinterpret_cast<const float4*>(p);
                rb[j][0] = bfbits(v.x); rb[j][1] = bfbits(v.y);
                rb[j][2] = bfbits(v.z); rb[j][3] = bfbits(v.w);
            } else {
                ushort4 v = *reinterpret_cast<const ushort4*>(p);
                rb[j][0] = v.x; rb[j][1] = v.y; rb[j][2] = v.z; rb[j][3] = v.w;
            }
        }
        int swz = ((px >> 2) & 7) * 8;
#pragma unroll
        for (int i = 0; i < 4; ++i) {
            union { unsigned short s[4]; uint2 v; } pk;
            pk.s[0] = rb[0][i]; pk.s[1] = rb[1][i];
            pk.s[2] = rb[2][i]; pk.s[3] = rb[3][i];
            *reinterpret_cast<uint2*>(&xs[px + i][ic ^ swz]) = pk.v;
        }
    }
    __syncthreads();

    int pxw = w_px * 32;

    bf16x8 bvreg[NKS][2];
#pragma unroll
    for (int ks = 0; ks < NKS; ++ks) {
        int koff = ks * 32 + lk * 8;
#pragma unroll
        for (int nf = 0; nf < 2; ++nf) {
            int px = pxw + nf * 16 + l15;
            int swzr = ((px >> 2) & 7) * 8;
            bvreg[ks][nf] = *reinterpret_cast<const bf16x8*>(&xs[px][koff ^ swzr]);
        }
    }

    __builtin_amdgcn_s_setprio(1);
#pragma unroll 1
    for (int ot = 0; ot < OCT; ++ot) {
        int ocw = ot * 64 + w_oc * 32;
        int oc16g = ot * 4 + w_oc * 2;
        f32x4 acc[2][2];
#pragma unroll
        for (int mi = 0; mi < 2; ++mi)
#pragma unroll
            for (int r = 0; r < 4; ++r) {
                float bz = bias[ocw + mi * 16 + lk * 4 + r];
#pragma unroll
                for (int nf = 0; nf < 2; ++nf) acc[mi][nf][r] = bz;
            }

#pragma unroll
        for (int ks = 0; ks < NKS; ++ks) {
            bf16x8 a[2];
#pragma unroll
            for (int mi = 0; mi < 2; ++mi)
                a[mi] = *reinterpret_cast<const bf16x8*>(
                    &Wb[((long long)(oc16g + mi) * NKS + ks) * 512 + lane * 8]);
#pragma unroll
            for (int mi = 0; mi < 2; ++mi)
#pragma unroll
                for (int nf = 0; nf < 2; ++nf)
                    acc[mi][nf] = __builtin_amdgcn_mfma_f32_16x16x32_bf16(
                        a[mi], bvreg[ks][nf], acc[mi][nf], 0, 0, 0);
        }

#pragma unroll
        for (int mi = 0; mi < 2; ++mi)
#pragma unroll
            for (int nf = 0; nf < 2; ++nf) {
                int x = pxw + nf * 16 + l15;
#pragma unroll
                for (int r = 0; r < 4; ++r) {
                    int oc = ocw + mi * 16 + lk * 4 + r;
                    stF(&out[(long long)b * bs_out + (long long)oc * NPIX + nb + x],
                        acc[mi][nf][r]);
                }
            }
    }
    __builtin_amdgcn_s_setprio(0);
}

template <typename TI, typename TO, int IC, int OCT, int ICPAD>
__global__ __launch_bounds__(256) void gemm1x1_allK_kernel(
    const TI* __restrict__ in0, long long bs0,
    const TI* __restrict__ in1, long long bs1, int ic_split,
    const unsigned short* __restrict__ Wbf, long long w_bs,
    const float* __restrict__ bias,
    TO* __restrict__ out, long long bs_out)
{
    __shared__ unsigned short xs[64][ICPAD];
    gemm1x1_body<TI, TO, IC, OCT, ICPAD>(in0, bs0, in1, bs1, ic_split,
                                         Wbf, w_bs, bias, out, bs_out, xs);
}

// Dual variant: blockIdx.y selects set A (k) or set B (v).
template <typename TI, typename TO, int IC, int OCT, int ICPAD>
__global__ __launch_bounds__(256) void gemm1x1_dual_kernel(
    const TI* __restrict__ in0a, const TI* __restrict__ in1a,
    const unsigned short* __restrict__ Wa, const float* __restrict__ biasa,
    TO* __restrict__ outa,
    const TI* __restrict__ in0b, const TI* __restrict__ in1b,
    const unsigned short* __restrict__ Wb_, const float* __restrict__ biasb,
    TO* __restrict__ outb,
    long long bs0, long long bs1, int ic_split, long long bs_out)
{
    __shared__ unsigned short xs[64][ICPAD];
    int y = blockIdx.y;
    gemm1x1_body<TI, TO, IC, OCT, ICPAD>(
        y ? in0b : in0a, bs0, y ? in1b : in1a, bs1, ic_split,
        y ? Wb_ : Wa, 0, y ? biasb : biasa, y ? outb : outa, bs_out, xs);
}

// ---------------------------------------------------------------------------
// Grouped / depthwise 3x3 conv, pad 1 — register sliding window.
// ---------------------------------------------------------------------------
template <int GIN, int GOUT, int ROWS>
__global__ __launch_bounds__(256) void dwconv3x3_kernel(
    const bf16* __restrict__ in, const float* __restrict__ Wm,
    const float* __restrict__ bias, bf16* __restrict__ out, int groups)
{
    __shared__ float xs[GIN][ROWS + 2][136];
    int tid = threadIdx.x;
    int g = blockIdx.y;
    int b = blockIdx.z;
    int y0 = blockIdx.x * ROWS;
    long long bsin = (long long)groups * GIN * NPIX;
    long long bsout = (long long)groups * GOUT * NPIX;
    const bf16* inb = in + (long long)b * bsin;

    constexpr int NLOAD = GIN * (ROWS + 2) * 32;
    for (int idx = tid; idx < NLOAD; idx += 256) {
        int seg = idx & 31;
        int r = (idx >> 5) % (ROWS + 2);
        int ic = idx / (32 * (ROWS + 2));
        int yy = y0 + r - 1;
        float4 f = {0.f, 0.f, 0.f, 0.f};
        if (yy >= 0 && yy < HH) {
            ushort4 u = *reinterpret_cast<const ushort4*>(
                &inb[(long long)(g * GIN + ic) * NPIX + yy * WW + seg * 4]);
            f.x = b2f(u.x); f.y = b2f(u.y); f.z = b2f(u.z); f.w = b2f(u.w);
        }
        *reinterpret_cast<float4*>(&xs[ic][r][seg * 4 + 4]) = f;
    }
    for (int idx = tid; idx < GIN * (ROWS + 2); idx += 256) {
        int r = idx % (ROWS + 2), ic = idx / (ROWS + 2);
        xs[ic][r][3] = 0.f;
        xs[ic][r][132] = 0.f;
    }
    __syncthreads();

    int x = tid & 127;
    int half = tid >> 7;
    constexpr int HR = ROWS / 2;
    int ry0 = half * HR;

    float wreg[GOUT][GIN][9];
    float bz[GOUT];
#pragma unroll
    for (int oc = 0; oc < GOUT; ++oc) {
        bz[oc] = bias[g * GOUT + oc];
#pragma unroll
        for (int ic = 0; ic < GIN; ++ic)
#pragma unroll
            for (int t = 0; t < 9; ++t)
                wreg[oc][ic][t] = Wm[((long long)(g * GOUT + oc) * GIN + ic) * 9 + t];
    }

    float win[GIN][3][3];
#pragma unroll
    for (int ic = 0; ic < GIN; ++ic)
#pragma unroll
        for (int pr = 0; pr < 2; ++pr)
#pragma unroll
            for (int kx = 0; kx < 3; ++kx)
                win[ic][pr][kx] = xs[ic][ry0 + pr][x + 3 + kx];

#pragma unroll
    for (int rr = 0; rr < HR; ++rr) {
#pragma unroll
        for (int ic = 0; ic < GIN; ++ic)
#pragma unroll
            for (int kx = 0; kx < 3; ++kx)
                win[ic][(rr + 2) % 3][kx] = xs[ic][ry0 + rr + 2][x + 3 + kx];
#pragma unroll
        for (int oc = 0; oc < GOUT; ++oc) {
            float acc = bz[oc];
#pragma unroll
            for (int ic = 0; ic < GIN; ++ic)
#pragma unroll
                for (int ky = 0; ky < 3; ++ky)
#pragma unroll
                    for (int kx = 0; kx < 3; ++kx)
                        acc = fmaf(wreg[oc][ic][ky * 3 + kx],
                                   win[ic][(rr + ky) % 3][kx], acc);
            stF(&out[(long long)b * bsout + (long long)(g * GOUT + oc) * NPIX
                     + (y0 + ry0 + rr) * WW + x], acc);
        }
    }
}

// ---------------------------------------------------------------------------
// NCHW fp32 -> NHWC bf16 transpose-convert.
// ---------------------------------------------------------------------------
__global__ __launch_bounds__(256) void nchw2nhwc_kernel(
    const float* __restrict__ in, unsigned short* __restrict__ outp)
{
    __shared__ float xs[192][65];
    int tid = threadIdx.x;
    int y = blockIdx.x >> 1;
    int x0 = (blockIdx.x & 1) * 64;
    int b = blockIdx.z;

    for (int idx = tid; idx < 192 * 64; idx += 256) {
        int ic = idx >> 6, px = idx & 63;
        xs[ic][px] = in[(((long long)b * CDIM + ic) << 14) + y * WW + x0 + px];
    }
    __syncthreads();
    for (int idx = tid; idx < 64 * 24; idx += 256) {
        int px = idx / 24, grp = idx % 24;
        union { unsigned short u[8]; uint4 v; } pk;
#pragma unroll
        for (int j = 0; j < 8; ++j) pk.u[j] = bfbits(xs[grp * 8 + j][px]);
        *reinterpret_cast<uint4*>(
            &outp[(((long long)b * HH + y) * WW + x0 + px) * CDIM + grp * 8]) = pk.v;
    }
}

// ---------------------------------------------------------------------------
// Dense 3x3 conv 192->384 via MFMA implicit GEMM, 2-output-row tiles,
// distinct-oc waves, double-buffered global_load_lds staging (R18 best):
// xs[2][4][66][64] (67.6 KB -> 2 blocks/CU), ONE barrier per chunk, next
// chunk's loads issued right after the barrier into the idle buffer.
// ---------------------------------------------------------------------------
__global__ __launch_bounds__(256) void conv3x3_mfma_kernel(
    const unsigned short* __restrict__ Xbf,
    const unsigned short* __restrict__ Wc,
    const float* __restrict__ bias,
    const unsigned short* __restrict__ zsrc,
    bf16* __restrict__ out)
{
    __shared__ unsigned short xs[2][4][66][64];
    int tid = threadIdx.x;
    int lane = tid & 63;
    int wave = tid >> 6;
    int l15 = lane & 15;
    int lk = lane >> 4;

    int ypair = blockIdx.x >> 1;
    int xstart = (blockIdx.x & 1) * 64;
    int y0 = ypair * 2;
    int b = blockIdx.z;
    int ocw = blockIdx.y * 128 + wave * 32;
    int oc16g = blockIdx.y * 8 + wave * 2;

    f32x4 acc[2][2][4];  // [yo][mi][nf]
#pragma unroll
    for (int mi = 0; mi < 2; ++mi)
#pragma unroll
        for (int r = 0; r < 4; ++r) {
            float bz = bias[ocw + mi * 16 + lk * 4 + r];
#pragma unroll
            for (int yo = 0; yo < 2; ++yo)
#pragma unroll
                for (int nf = 0; nf < 4; ++nf) acc[yo][mi][nf][r] = bz;
        }

#define CONV_GLL_CHUNK(IC0, BUF)                                               \
    {                                                                          \
        _Pragma("unroll")                                                      \
        for (int k = 0; k < 9; ++k) {                                          \
            if (k < 8 || wave == 0) {                                          \
                int idx = (k << 8) + (wave << 6) + lane;                       \
                int r = idx / 528;                                             \
                int rem = idx - r * 528;                                       \
                int col = rem >> 3;                                            \
                int grp = rem & 7;                                             \
                int g = grp ^ (col & 7);                                       \
                int yy = y0 + r - 1;                                           \
                int xx = xstart + col - 1;                                     \
                const unsigned short* src =                                    \
                    (yy >= 0 && yy < HH && xx >= 0 && xx < WW)                 \
                        ? &Xbf[(((long long)b * HH + yy) * WW + xx) * CDIM     \
                               + (IC0) + g * 8]                                \
                        : zsrc;                                                \
                unsigned short* lptr = ((unsigned short*)xs) +                 \
                    (BUF) * (4 * 66 * 64) + (((k << 8) + (wave << 6)) << 3);   \
                __builtin_amdgcn_global_load_lds(                              \
                    (const __attribute__((address_space(1))) unsigned int*)src,\
                    (__attribute__((address_space(3))) unsigned int*)lptr,     \
                    16, 0, 0);                                                 \
            }                                                                  \
        }                                                                      \
    }

    CONV_GLL_CHUNK(0, 0);

#pragma unroll
    for (int chunk = 0; chunk < 3; ++chunk) {
        __syncthreads();  // drains vmcnt: this chunk's buffer is ready
        if (chunk == 0)      { CONV_GLL_CHUNK(64, 1); }   // overlap with compute
        else if (chunk == 1) { CONV_GLL_CHUNK(128, 0); }
        int buf = chunk & 1;
        __builtin_amdgcn_s_setprio(1);

#pragma unroll
        for (int kx = 0; kx < 3; ++kx) {
#pragma unroll
            for (int ks = 0; ks < 2; ++ks) {
                int ksg = chunk * 2 + ks;
                bf16x8 aw[3][2];
#pragma unroll
                for (int ky = 0; ky < 3; ++ky)
#pragma unroll
                    for (int mi = 0; mi < 2; ++mi)
                        aw[ky][mi] = *reinterpret_cast<const bf16x8*>(
                            &Wc[((((long long)(oc16g + mi) * 9 + ky * 3 + kx) * 6 + ksg) << 9)
                                + lane * 8]);
#pragma unroll
                for (int r = 0; r < 4; ++r) {
                    bf16x8 bv[4];
#pragma unroll
                    for (int nf = 0; nf < 4; ++nf) {
                        int col = nf * 16 + l15 + kx;
                        int slot = (ks * 4 + lk) ^ (col & 7);
                        bv[nf] = *reinterpret_cast<const bf16x8*>(
                            &xs[buf][r][col][slot * 8]);
                    }
#pragma unroll
                    for (int yo = 0; yo < 2; ++yo) {
                        int ky = r - yo;
                        if (ky >= 0 && ky <= 2) {
#pragma unroll
                            for (int mi = 0; mi < 2; ++mi)
#pragma unroll
                                for (int nf = 0; nf < 4; ++nf)
                                    acc[yo][mi][nf] = __builtin_amdgcn_mfma_f32_16x16x32_bf16(
                                        aw[ky][mi], bv[nf], acc[yo][mi][nf], 0, 0, 0);
                        }
                    }
                }
            }
        }
        __builtin_amdgcn_s_setprio(0);
    }

#pragma unroll
    for (int yo = 0; yo < 2; ++yo)
#pragma unroll
        for (int mi = 0; mi < 2; ++mi)
#pragma unroll
            for (int nf = 0; nf < 4; ++nf) {
                int x = xstart + nf * 16 + l15;
#pragma unroll
                for (int r = 0; r < 4; ++r) {
                    int oc = ocw + mi * 16 + lk * 4 + r;
                    stF(&out[(((long long)b * 384 + oc) << 14) + (y0 + yo) * WW + x],
                        acc[yo][mi][nf][r]);
                }
            }
}

// ---------------------------------------------------------------------------
// Gram + sumsq via MFMA.
// ---------------------------------------------------------------------------
__global__ __launch_bounds__(256) void gram_mfma_kernel(
    const unsigned short* __restrict__ q, long long bsq,
    const unsigned short* __restrict__ k, long long bsk,
    const unsigned short* __restrict__ v, long long bsv,
    float* __restrict__ ssq, float* __restrict__ gram)
{
    __shared__ float gl[4][24][25];
    int bh = blockIdx.x;
    int b = bh >> 3, h = bh & 7;
    int n0 = blockIdx.y * 1024;
    int tid = threadIdx.x;
    int lane = tid & 63;
    int wave = tid >> 6;
    int l15 = lane & 15;
    int lk = lane >> 4;

    const unsigned short* qb = q + (long long)b * bsq + (long long)(h * CP) * NPIX;
    const unsigned short* kb = k + (long long)b * bsk + (long long)(h * CP) * NPIX;
    const unsigned short* vb = v + (long long)b * bsv + (long long)(h * CP) * NPIX;

    f32x4 acc[2][2], aqq[2], akk[2], avv[2];
#pragma unroll
    for (int mt = 0; mt < 2; ++mt) {
#pragma unroll
        for (int nt = 0; nt < 2; ++nt) acc[mt][nt] = {0.f, 0.f, 0.f, 0.f};
        aqq[mt] = {0.f, 0.f, 0.f, 0.f};
        akk[mt] = {0.f, 0.f, 0.f, 0.f};
        avv[mt] = {0.f, 0.f, 0.f, 0.f};
    }

#pragma unroll 2
    for (int st = 0; st < 8; ++st) {
        int px = n0 + wave * 256 + st * 32 + lk * 8;
        bf16x8 aq[2], bk[2], av[2];
#pragma unroll
        for (int mt = 0; mt < 2; ++mt) {
            long long off = (long long)(mt * 16 + l15) * NPIX + px;
            aq[mt] = *reinterpret_cast<const bf16x8*>(&qb[off]);
            bk[mt] = *reinterpret_cast<const bf16x8*>(&kb[off]);
            av[mt] = *reinterpret_cast<const bf16x8*>(&vb[off]);
        }
#pragma unroll
        for (int mt = 0; mt < 2; ++mt)
#pragma unroll
            for (int nt = 0; nt < 2; ++nt)
                acc[mt][nt] = __builtin_amdgcn_mfma_f32_16x16x32_bf16(
                    aq[mt], bk[nt], acc[mt][nt], 0, 0, 0);
#pragma unroll
        for (int mt = 0; mt < 2; ++mt) {
            aqq[mt] = __builtin_amdgcn_mfma_f32_16x16x32_bf16(aq[mt], aq[mt], aqq[mt], 0, 0, 0);
            akk[mt] = __builtin_amdgcn_mfma_f32_16x16x32_bf16(bk[mt], bk[mt], akk[mt], 0, 0, 0);
            avv[mt] = __builtin_amdgcn_mfma_f32_16x16x32_bf16(av[mt], av[mt], avv[mt], 0, 0, 0);
        }
    }

    if (lk == (l15 >> 2)) {
        int r = l15 & 3;
#pragma unroll
        for (int mt = 0; mt < 2; ++mt) {
            int ch = mt * 16 + l15;
            if (ch < CP) {
                int o = b * CDIM + h * CP + ch;
                atomicAdd(&ssq[o], aqq[mt][r]);
                atomicAdd(&ssq[NB * CDIM + o], akk[mt][r]);
                atomicAdd(&ssq[2 * NB * CDIM + o], avv[mt][r]);
            }
        }
    }

#pragma unroll
    for (int mt = 0; mt < 2; ++mt)
#pragma unroll
        for (int nt = 0; nt < 2; ++nt)
#pragma unroll
            for (int r = 0; r < 4; ++r) {
                int cq = mt * 16 + lk * 4 + r;
                int ck = nt * 16 + l15;
                if (cq < CP && ck < CP) gl[wave][cq][ck] = acc[mt][nt][r];
            }
    __syncthreads();
    for (int e = tid; e < CP * CP; e += 256) {
        int cq = e / CP, ck = e % CP;
        float s = gl[0][cq][ck] + gl[1][cq][ck] + gl[2][cq][ck] + gl[3][cq][ck];
        atomicAdd(&gram[(long long)bh * (CP * CP) + e], s);
    }
}

// ---------------------------------------------------------------------------
// Softmax + fold norms + proj -> per-batch M, packed layout (parallel).
// ---------------------------------------------------------------------------
__global__ __launch_bounds__(256) void build_M_kernel(
    const float* __restrict__ ssq, const float* __restrict__ gram,
    const float* __restrict__ temp, const float* __restrict__ proj_w,
    unsigned short* __restrict__ Mout)
{
    __shared__ float A[HEADS][CP][CP + 1];
    __shared__ float nv[CDIM];
    int b = blockIdx.x;
    int ocg = blockIdx.y;           // 0..23, 8 ocs each
    int tid = threadIdx.x;

    if (tid < CDIM)
        nv[tid] = fmaxf(sqrtf(ssq[2 * (NB * CDIM) + b * CDIM + tid]), 1e-12f);
    __syncthreads();
    if (tid < CDIM) {
        int h = tid / CP, cq = tid % CP;
        float t = temp[h];
        float nq = fmaxf(sqrtf(ssq[0 * (NB * CDIM) + b * CDIM + tid]), 1e-12f);
        float row[CP];
        float m = -1e30f;
#pragma unroll
        for (int ck = 0; ck < CP; ++ck) {
            float nk = fmaxf(sqrtf(ssq[1 * (NB * CDIM) + b * CDIM + h * CP + ck]), 1e-12f);
            float g = gram[(long long)b * (HEADS * 576) + h * 576 + cq * CP + ck];
            g = g / (nq * nk) * t;
            row[ck] = g;
            m = fmaxf(m, g);
        }
        float s = 0.f;
#pragma unroll
        for (int ck = 0; ck < CP; ++ck) { row[ck] = __expf(row[ck] - m); s += row[ck]; }
        float inv = 1.f / s;
#pragma unroll
        for (int ck = 0; ck < CP; ++ck)
            A[h][cq][ck] = row[ck] * inv / nv[h * CP + ck];
    }
    __syncthreads();
    for (int e = tid; e < 8 * CDIM; e += 256) {
        int oc = ocg * 8 + e / CDIM, d = e % CDIM;
        int h2 = d / CP, ck = d % CP;
        float acc = 0.f;
#pragma unroll
        for (int cq = 0; cq < CP; ++cq)
            acc = fmaf(proj_w[(long long)oc * CDIM + h2 * CP + cq], A[h2][cq][ck], acc);
        int oc16 = oc >> 4, l15 = oc & 15;
        int ksg = d >> 5, lk = (d >> 3) & 3, j = d & 7;
        int lanep = lk * 16 + l15;
        Mout[(long long)b * (CDIM * CDIM) + (((oc16 * 6 + ksg) << 6) + lanep) * 8 + j] =
            bfbits(acc);
    }
}

// ---------------------------------------------------------------------------
// Workspace layout (< 202 MB).
// ---------------------------------------------------------------------------
extern "C" void kernel_launch(void* const* d_in, const int* in_sizes, int n_in,
                              void* d_out, int out_size, void* d_ws, size_t ws_size,
                              hipStream_t stream)
{
    const float* x      = (const float*)d_in[0];
    const float* x_mask = (const float*)d_in[1];
    const float* temp   = (const float*)d_in[2];
    const float* q_w    = (const float*)d_in[3];
    const float* q_b    = (const float*)d_in[4];
    const float* qdw_w  = (const float*)d_in[5];
    const float* qdw_b  = (const float*)d_in[6];
    const float* kv_w   = (const float*)d_in[7];
    const float* kv_b   = (const float*)d_in[8];
    const float* kvdw_w = (const float*)d_in[9];
    const float* kvdw_b = (const float*)d_in[10];
    const float* newk_w = (const float*)d_in[11];
    const float* newk_b = (const float*)d_in[12];
    const float* newv_w = (const float*)d_in[13];
    const float* newv_b = (const float*)d_in[14];
    const float* proj_w = (const float*)d_in[15];
    const float* proj_b = (const float*)d_in[16];

    char* wsb = (char*)d_ws;
    bf16* A  = (bf16*)wsb;
    bf16* Bq = (bf16*)(wsb + 75497472);
    bf16* C  = (bf16*)(wsb + 150994944);
    unsigned short* qwb   = (unsigned short*)Bq;                    // 110,592
    unsigned short* Wpack = (unsigned short*)C;                     // 663,552
    unsigned short* Xbf   = (unsigned short*)C + 663552;            // 12,582,912
    float* stats = (float*)(wsb + 201326592);
    float* ssq  = stats;                                            // 2304
    float* gram = ssq + 2304;                                       // 18432
    unsigned short* nkb = (unsigned short*)(stats + 20736);         // 73,728
    unsigned short* nvb = nkb + 73728;                              // 73,728
    unsigned short* Mbf = nvb + 73728;                              // 147,456

    const long long N = NPIX;
    float* out = (float*)d_out;

    // P0: fused prep — zero stats + all weight packs (1 launch)
    prep_kernel<<<3681, 256, 0, stream>>>(
        stats, q_w, qwb, newk_w, nkb, newv_w, nvb, kv_w, Wpack);

    // S1: qkv1 = conv1x1(x, q_w) : 192 -> 576 (fp32 in, bf16 out) -> A
    gemm1x1_allK_kernel<float, bf16, 192, 9, 200><<<dim3(256, 1, 4), 256, 0, stream>>>(
        x, 192 * N, x, 0, 192, qwb, 0, q_b, A, 576 * N);

    // S2: qkv = grouped 3x3 (groups=192, 3in/3out) -> B (ROWS=16)
    dwconv3x3_kernel<3, 3, 16><<<dim3(8, 192, 4), 256, 0, stream>>>(
        A, qdw_w, qdw_b, Bq, 192);

    // NHWC convert into C (x_mask -> Xbf)
    nchw2nhwc_kernel<<<dim3(256, 1, 4), 256, 0, stream>>>(x_mask, Xbf);

    // S3: kv1 = dense conv3x3(x_mask) 192->384 via MFMA -> A[0:25.17M)
    conv3x3_mfma_kernel<<<dim3(128, 3, 4), 256, 0, stream>>>(
        Xbf, Wpack, kv_b, (const unsigned short*)stats, A);

    // S4: kv2 = depthwise 3x3 (384 groups) -> C (ROWS=32)
    dwconv3x3_kernel<1, 1, 32><<<dim3(4, 384, 4), 256, 0, stream>>>(
        A, kvdw_w, kvdw_b, C, 384);

    // S5: k_new / v_new = conv1x1 of concat (IC=384), fused dual launch
    bf16* k_new = A;
    bf16* v_new = A + 12582912;
    gemm1x1_dual_kernel<bf16, bf16, 384, 3, 392><<<dim3(256, 2, 4), 256, 0, stream>>>(
        Bq + 192 * N, C, nkb, newk_b, k_new,
        Bq + 384 * N, C + 192 * N, nvb, newv_b, v_new,
        576 * N, 384 * N, 192, 192 * N);

    // S6: sumsq(q,k,v) + Gram(q,k) via MFMA
    gram_mfma_kernel<<<dim3(32, 16), 256, 0, stream>>>(
        (const unsigned short*)Bq, 576 * N,
        (const unsigned short*)k_new, 192 * N,
        (const unsigned short*)v_new, 192 * N, ssq, gram);

    // S7: softmax + fold v-norm + proj -> per-batch M (bf16, packed layout)
    build_M_kernel<<<dim3(4, 24), 256, 0, stream>>>(ssq, gram, temp, proj_w, Mbf);

    // S8: out = M_b @ v_new + proj_b (bf16 in, fp32 out)
    gemm1x1_allK_kernel<bf16, float, 192, 3, 200><<<dim3(256, 1, 4), 256, 0, stream>>>(
        v_new, 192 * N, v_new, 0, 192, Mbf, (long long)CDIM * CDIM, proj_b, out, 192 * N);
}